// Round 16
// baseline (262.653 us; speedup 1.0000x reference)
//
#include <hip/hip_runtime.h>
#include <math.h>

#define BB 4
#define CC 128
#define CRR 32
#define DD 24
#define HH 96
#define WW 320
#define HWW (HH*WW)   // 30720
#define NBLK 240      // conv blocks per batch (48 h-pairs x 5 w-tiles)

typedef __attribute__((ext_vector_type(8))) short bs8;     // 8 bf16 (4 VGPR)
typedef __attribute__((ext_vector_type(4))) float f32x4;   // MFMA acc
typedef __attribute__((ext_vector_type(4))) int   i32x4;

static __device__ __forceinline__ unsigned short f2bf(float x) {
    unsigned int u = __float_as_uint(x);
    unsigned int r = (u + 0x7fffu + ((u >> 16) & 1u)) >> 16;   // RNE
    return (unsigned short)r;
}

// ---------------------------------------------------------------------------
// Merged repack: q_w/k_w + ce_w + redu_w -> bf16 fragments. 159744 elems.
// ---------------------------------------------------------------------------
__global__ __launch_bounds__(256) void repack_all_kernel(
    const float* __restrict__ q_w, const float* __restrict__ k_w,
    const float* __restrict__ ce_w, const float* __restrict__ redu_w,
    unsigned short* __restrict__ wqk, unsigned short* __restrict__ wce,
    unsigned short* __restrict__ wb)
{
    int idx = blockIdx.x * 256 + threadIdx.x;
    if (idx < 8192) {
        int j   = idx & 7;
        int l   = (idx >> 3) & 63;
        int kc  = (idx >> 9) & 3;
        int ofh = (idx >> 11) & 1;
        int g   = idx >> 12;
        const float* w = g ? k_w : q_w;
        int oc = ofh * 16 + (l & 15);
        int ic = kc * 32 + (l >> 4) * 8 + j;
        wqk[idx] = f2bf(w[oc * CC + ic]);
    } else if (idx < 12288) {
        int i   = idx - 8192;
        int j   = i & 7;
        int l   = (i >> 3) & 63;
        int ofg = (i >> 9) & 7;
        int oc = ofg * 16 + (l & 15);
        int ic = (l >> 4) * 8 + j;
        wce[i] = f2bf(ce_w[oc * CRR + ic]);
    } else {
        int i2 = idx - 12288;                    // < 147456
        int j    = i2 & 7;
        int l    = (i2 >> 3) & 63;
        int rest = i2 >> 9;
        int ocf  = rest & 7;
        int kc   = (rest >> 3) & 3;
        int tap  = rest >> 5;                    // 0..8
        int oc = ocf * 16 + (l & 15);
        int ic = kc * 32 + (l >> 4) * 8 + j;
        wb[i2] = f2bf(redu_w[(size_t)(oc * CC + ic) * 9 + tap]);
    }
}

// ---------------------------------------------------------------------------
// Kernel 1: q/k 1x1 conv + bias + l2norm via bf16 MFMA (weights = A operand).
// Output layout: CHANNEL-LAST  ws_q/ws_k[(b*HWW+px)*32 + c].
// ---------------------------------------------------------------------------
__global__ __launch_bounds__(256) void qk_mfma_kernel(
    const float* __restrict__ t_feat, const float* __restrict__ s_feat,
    const unsigned short* __restrict__ wqk,
    const float* __restrict__ q_b, const float* __restrict__ k_b,
    float* __restrict__ ws_q, float* __restrict__ ws_k)
{
    __shared__ __align__(16) unsigned char lds[2 * 64 * 16 * 16];   // 32 KB
    int tid  = threadIdx.x;
    int lane = tid & 63;
    int wid  = __builtin_amdgcn_readfirstlane(tid >> 6);
    int g = wid >> 1, ofh = wid & 1;
    int p0 = blockIdx.x * 64;
    int b = p0 / HWW, rem0 = p0 % HWW;

    for (int ci = tid; ci < 2 * 64 * 16; ci += 256) {
        int px   = ci & 63;
        int slot = (ci >> 6) & 15;
        int m    = ci >> 10;
        const float* src = (m ? s_feat : t_feat)
                         + (size_t)b * CC * HWW + (size_t)(slot * 8) * HWW + rem0 + px;
        i32x4 u;
        #pragma unroll
        for (int j = 0; j < 4; ++j) {
            unsigned short lo = f2bf(src[(size_t)(2 * j) * HWW]);
            unsigned short hi = f2bf(src[(size_t)(2 * j + 1) * HWW]);
            u[j] = (int)((unsigned int)lo | ((unsigned int)hi << 16));
        }
        int addr = m * 16384 + px * 256 + ((slot ^ (px & 7)) << 4);
        *(i32x4*)(lds + addr) = u;
    }
    __syncthreads();

    int l15 = lane & 15, l4 = lane >> 4;
    f32x4 acc[4];
    #pragma unroll
    for (int pf = 0; pf < 4; ++pf) acc[pf] = (f32x4){0.f, 0.f, 0.f, 0.f};

    const bs8* wp = (const bs8*)wqk + (size_t)(g * 2 + ofh) * 4 * 64;
    #pragma unroll
    for (int kc = 0; kc < 4; ++kc) {
        bs8 bf = wp[kc * 64 + lane];
        #pragma unroll
        for (int pf = 0; pf < 4; ++pf) {
            int addr = g * 16384 + (pf * 16 + l15) * 256 + (((kc * 4 + l4) ^ (l15 & 7)) << 4);
            bs8 a = *(const bs8*)(lds + addr);
            acc[pf] = __builtin_amdgcn_mfma_f32_16x16x32_bf16(bf, a, acc[pf], 0, 0, 0);
        }
    }

    float4 bias4 = *(const float4*)((g ? k_b : q_b) + ofh * 16 + l4 * 4);
    float np[4];
    #pragma unroll
    for (int pf = 0; pf < 4; ++pf) {
        float s = 0.f;
        #pragma unroll
        for (int r = 0; r < 4; ++r) {
            float v = acc[pf][r] + ((const float*)&bias4)[r];
            acc[pf][r] = v;
            s = fmaf(v, v, s);
        }
        s += __shfl_xor(s, 16, 64);
        s += __shfl_xor(s, 32, 64);
        np[pf] = s;
    }
    __syncthreads();    // A tiles dead; reuse LDS for norm exchange
    float* fl = (float*)lds;   // [4 waves][64 px]
    if (l4 == 0) {
        #pragma unroll
        for (int pf = 0; pf < 4; ++pf)
            fl[(g * 2 + ofh) * 64 + pf * 16 + l15] = np[pf];
    }
    __syncthreads();

    float* dst = (g ? ws_k : ws_q) + ((size_t)b * HWW + rem0) * CRR;
    #pragma unroll
    for (int pf = 0; pf < 4; ++pf) {
        int px = pf * 16 + l15;
        float tot = fl[(g * 2) * 64 + px] + fl[(g * 2 + 1) * 64 + px];
        float inv = 1.f / fmaxf(sqrtf(tot), 1e-12f);
        float4 v;
        v.x = acc[pf][0] * inv; v.y = acc[pf][1] * inv;
        v.z = acc[pf][2] * inv; v.w = acc[pf][3] * inv;
        *(float4*)(dst + (size_t)px * CRR + ofh * 16 + l4 * 4) = v;
    }
}

// ---------------------------------------------------------------------------
// Kernel 2: sim + (no-max) online softmax + cost, single gather pass over
// an LDS-staged k-row segment.  One-sided halo (directs fixes shift sign).
// ---------------------------------------------------------------------------
#define SC_TILE 64
#define SC_NCOLS 114
__global__ __launch_bounds__(256) void simcost_kernel(
    const float* __restrict__ directs, const int* __restrict__ image_shape,
    const float* __restrict__ ws_q, const float* __restrict__ ws_k,
    float* __restrict__ prob_out, float* __restrict__ ws_cost)
{
    __shared__ __align__(16) unsigned char kl[SC_NCOLS * 128];
    int tid = threadIdx.x;
    int b = blockIdx.z, h = blockIdx.y, w0 = blockIdx.x * SC_TILE;

    float rel = 640.0f / (float)image_shape[3];
    float fscale = rel * directs[b] * (float)(WW - 1);
    int base = (fscale >= 0.f) ? w0 : (w0 - 49);

    const float* krow = ws_k + ((size_t)b * HWW + h * WW) * CRR;
    for (int i = tid; i < SC_NCOLS * 8; i += 256) {
        int col = i >> 3, j = i & 7;
        int gc = min(max(base + col, 0), WW - 1);
        float4 v = *(const float4*)(krow + (size_t)gc * CRR + j * 4);
        *(float4*)(kl + col * 128 + ((j ^ (col & 7)) << 4)) = v;
    }
    __syncthreads();

    int quarter = tid & 3;
    int pxl = tid >> 2;                       // 0..63
    int w = w0 + pxl;
    int rem = h * WW + w;
    size_t p = (size_t)b * HWW + rem;

    float4 q0, q1;
    {
        const float4* qb = (const float4*)(ws_q + p * CRR + quarter * 8);
        q0 = qb[0]; q1 = qb[1];
    }

    float e[DD];
    float Z = 0.f;
    float4 c0 = {0.f,0.f,0.f,0.f}, c1 = {0.f,0.f,0.f,0.f};
    int j0 = quarter * 2, j1 = quarter * 2 + 1;

    #pragma unroll
    for (int d = 0; d < DD; ++d) {
        float disp = 0.3f * (float)d / 23.0f;
        float fx = fminf(fmaxf((float)w + disp * fscale, 0.f), (float)(WW - 1));
        int ix0 = (int)floorf(fx);
        int ix1 = min(ix0 + 1, WW - 1);
        float w1 = fx - (float)ix0;
        int ca = ix0 - base, cb2 = ix1 - base;
        float4 a0 = *(const float4*)(kl + ca  * 128 + ((j0 ^ (ca  & 7)) << 4));
        float4 a1 = *(const float4*)(kl + ca  * 128 + ((j1 ^ (ca  & 7)) << 4));
        float4 b0 = *(const float4*)(kl + cb2 * 128 + ((j0 ^ (cb2 & 7)) << 4));
        float4 b1 = *(const float4*)(kl + cb2 * 128 + ((j1 ^ (cb2 & 7)) << 4));
        float4 w0v, w1v;
        w0v.x = fmaf(w1, b0.x - a0.x, a0.x);
        w0v.y = fmaf(w1, b0.y - a0.y, a0.y);
        w0v.z = fmaf(w1, b0.z - a0.z, a0.z);
        w0v.w = fmaf(w1, b0.w - a0.w, a0.w);
        w1v.x = fmaf(w1, b1.x - a1.x, a1.x);
        w1v.y = fmaf(w1, b1.y - a1.y, a1.y);
        w1v.z = fmaf(w1, b1.z - a1.z, a1.z);
        w1v.w = fmaf(w1, b1.w - a1.w, a1.w);
        float s = 0.f;
        s = fmaf(q0.x, w0v.x, s); s = fmaf(q0.y, w0v.y, s);
        s = fmaf(q0.z, w0v.z, s); s = fmaf(q0.w, w0v.w, s);
        s = fmaf(q1.x, w1v.x, s); s = fmaf(q1.y, w1v.y, s);
        s = fmaf(q1.z, w1v.z, s); s = fmaf(q1.w, w1v.w, s);
        s += __shfl_xor(s, 1, 64);
        s += __shfl_xor(s, 2, 64);
        float ee = __expf(s);
        e[d] = ee;
        Z += ee;
        c0.x = fmaf(ee, w0v.x, c0.x); c0.y = fmaf(ee, w0v.y, c0.y);
        c0.z = fmaf(ee, w0v.z, c0.z); c0.w = fmaf(ee, w0v.w, c0.w);
        c1.x = fmaf(ee, w1v.x, c1.x); c1.y = fmaf(ee, w1v.y, c1.y);
        c1.z = fmaf(ee, w1v.z, c1.z); c1.w = fmaf(ee, w1v.w, c1.w);
    }
    float inv = 1.f / Z;
    if (quarter == 0) {
        #pragma unroll
        for (int d = 0; d < DD; ++d)
            prob_out[((size_t)b * DD + d) * HWW + rem] = e[d] * inv;
    }
    c0.x *= inv; c0.y *= inv; c0.z *= inv; c0.w *= inv;
    c1.x *= inv; c1.y *= inv; c1.z *= inv; c1.w *= inv;
    float4* cb = (float4*)(ws_cost + p * CRR + quarter * 8);
    cb[0] = c0; cb[1] = c1;
}

// ---------------------------------------------------------------------------
// Kernel 2c: cost-expand via MFMA (weights = A) + alpha + fuse.
// Writes fused as bf16 CHANNEL-LAST [px][128].
// ---------------------------------------------------------------------------
__global__ __launch_bounds__(256) void fuse_mfma_kernel(
    const float* __restrict__ t_feat, const unsigned short* __restrict__ wce,
    const float* __restrict__ ce_b, const float* __restrict__ fa_w,
    const float* __restrict__ fa_b,
    const float* __restrict__ ws_cost, unsigned short* __restrict__ fused)
{
    __shared__ __align__(16) unsigned char ldsA[64 * 64];   // 64px x 32c bf16
    __shared__ float lds_pa[64][4];
    __shared__ float lds_alpha[64];
    int tid  = threadIdx.x;
    int lane = tid & 63;
    int wid  = __builtin_amdgcn_readfirstlane(tid >> 6);
    int p0 = blockIdx.x * 64;
    int b = p0 / HWW, rem0 = p0 % HWW;

    {   // stage cost tile bf16 (1 slot of 8ch per thread)
        int px = tid & 63, slot = tid >> 6;
        const float* src = ws_cost + (size_t)(p0 + px) * CRR + slot * 8;
        i32x4 u;
        #pragma unroll
        for (int j = 0; j < 4; ++j) {
            unsigned short lo = f2bf(src[2 * j]);
            unsigned short hi = f2bf(src[2 * j + 1]);
            u[j] = (int)((unsigned int)lo | ((unsigned int)hi << 16));
        }
        int addr = px * 64 + ((slot ^ (px & 3)) << 4);
        *(i32x4*)(ldsA + addr) = u;
    }
    __syncthreads();

    int l15 = lane & 15, l4 = lane >> 4;
    f32x4 acc[4][2];
    #pragma unroll
    for (int pf = 0; pf < 4; ++pf)
        #pragma unroll
        for (int of = 0; of < 2; ++of)
            acc[pf][of] = (f32x4){0.f, 0.f, 0.f, 0.f};

    const bs8* wp = (const bs8*)wce;
    #pragma unroll
    for (int pf = 0; pf < 4; ++pf) {
        int row = pf * 16 + l15;
        bs8 a = *(const bs8*)(ldsA + row * 64 + ((l4 ^ (l15 & 3)) << 4));
        #pragma unroll
        for (int of = 0; of < 2; ++of) {
            bs8 bf = wp[(wid * 2 + of) * 64 + lane];
            acc[pf][of] = __builtin_amdgcn_mfma_f32_16x16x32_bf16(bf, a, acc[pf][of], 0, 0, 0);
        }
    }

    // epilogue: oc = wid*32 + of*16 + l4*4 + r ; px = pf*16 + l15
    const float* tb = t_feat + (size_t)b * CC * HWW + rem0;
    float tv[4][2][4];
    float pa[4];
    #pragma unroll
    for (int pf = 0; pf < 4; ++pf) pa[pf] = 0.f;

    #pragma unroll
    for (int of = 0; of < 2; ++of) {
        int ocb = wid * 32 + of * 16 + l4 * 4;
        float4 cb4 = *(const float4*)(ce_b + ocb);
        float4 f14 = *(const float4*)(fa_w + ocb);
        float4 f24 = *(const float4*)(fa_w + CC + ocb);
        #pragma unroll
        for (int pf = 0; pf < 4; ++pf) {
            int px = pf * 16 + l15;
            #pragma unroll
            for (int r = 0; r < 4; ++r) {
                float ce = acc[pf][of][r] + ((const float*)&cb4)[r];
                acc[pf][of][r] = ce;
                float t = tb[(size_t)(ocb + r) * HWW + px];
                tv[pf][of][r] = t;
                pa[pf] = fmaf(((const float*)&f14)[r], t,
                              fmaf(((const float*)&f24)[r], ce, pa[pf]));
            }
        }
    }
    #pragma unroll
    for (int pf = 0; pf < 4; ++pf) {
        float v = pa[pf];
        v += __shfl_xor(v, 16, 64);
        v += __shfl_xor(v, 32, 64);
        if (l4 == 0) lds_pa[pf * 16 + l15][wid] = v;
    }
    __syncthreads();
    if (tid < 64) {
        float s = lds_pa[tid][0] + lds_pa[tid][1] + lds_pa[tid][2] + lds_pa[tid][3] + fa_b[0];
        lds_alpha[tid] = 1.f / (1.f + expf(-s));
    }
    __syncthreads();

    #pragma unroll
    for (int pf = 0; pf < 4; ++pf) {
        int px = pf * 16 + l15;
        float alpha = lds_alpha[px];
        unsigned short* dst = fused + (size_t)(p0 + px) * CC;
        #pragma unroll
        for (int of = 0; of < 2; ++of) {
            int ocb = wid * 32 + of * 16 + l4 * 4;
            float v0 = alpha * tv[pf][of][0] + (1.f - alpha) * acc[pf][of][0];
            float v1 = alpha * tv[pf][of][1] + (1.f - alpha) * acc[pf][of][1];
            float v2 = alpha * tv[pf][of][2] + (1.f - alpha) * acc[pf][of][2];
            float v3 = alpha * tv[pf][of][3] + (1.f - alpha) * acc[pf][of][3];
            uint2 u;
            u.x = (unsigned int)f2bf(v0) | ((unsigned int)f2bf(v1) << 16);
            u.y = (unsigned int)f2bf(v2) | ((unsigned int)f2bf(v3) << 16);
            *(uint2*)(dst + ocb) = u;
        }
    }
}

// ---------------------------------------------------------------------------
// Kernel 3: 3x3 reflect-pad conv via bf16 MFMA (weights = A operand).
// 2 output rows per block (4-row slab), split-K 2 phases, 33.8 KB LDS,
// 4 blocks/CU.  B-frag loaded once per (tap,kc), reused across both rows
// and 4 pf -> B L2 traffic halved vs R11.  f32 full-line output stores;
// coalesced [b][blk][oc] pool partials; XCD-bijective block swizzle
// (960 blocks = 8 XCDs x 120).
// ---------------------------------------------------------------------------
__global__ __launch_bounds__(256, 4) void conv_mfma_kernel(
    const unsigned short* __restrict__ fused, const unsigned short* __restrict__ wb,
    float* __restrict__ out_conv, float* __restrict__ pool_partial)
{
    __shared__ __align__(16) unsigned char lds[4 * 66 * 128];   // 33,792 B
    int tid  = threadIdx.x;
    int lane = tid & 63;
    int wid  = __builtin_amdgcn_readfirstlane(tid >> 6);

    int bid = blockIdx.x;
    int swz = (bid & 7) * 120 + (bid >> 3);
    int x  = swz % 5;
    int h2 = (swz / 5) % (HH / 2);
    int b  = swz / (5 * (HH / 2));
    int w0 = x * 64;
    int h0 = h2 * 2;

    const unsigned short* fb = fused + (size_t)b * HWW * CC;

    int l15 = lane & 15, l4 = lane >> 4;
    const bs8* wbp = (const bs8*)wb;

    f32x4 acc[2][4][2];              // [row][pf][of]
    #pragma unroll
    for (int ri = 0; ri < 2; ++ri)
        #pragma unroll
        for (int pf = 0; pf < 4; ++pf)
            #pragma unroll
            for (int of = 0; of < 2; ++of)
                acc[ri][pf][of] = (f32x4){0.f, 0.f, 0.f, 0.f};

    // precompute column bases and the 6 swizzle-XOR variants (8-slot space)
    int basex[3], xr6[3][2];
    #pragma unroll
    for (int kx = 0; kx < 3; ++kx) {
        basex[kx] = (l15 + kx) * 128;
        #pragma unroll
        for (int kcl = 0; kcl < 2; ++kcl)
            xr6[kx][kcl] = ((kcl * 4 + l4) ^ ((l15 + kx) & 7)) << 4;
    }

    #pragma unroll
    for (int p = 0; p < 2; ++p) {
        if (p > 0) __syncthreads();
        // stage rows h0-1..h0+2, channels [p*64, p*64+64)
        for (int ci = tid; ci < 4 * 66 * 8; ci += 256) {
            int row  = ci / 528;
            int r2   = ci - row * 528;
            int col  = r2 >> 3;
            int slot = r2 & 7;
            int grow = h0 - 1 + row; grow = grow < 0 ? 1 : (grow > HH - 1 ? HH - 2 : grow);
            int gcol = w0 - 1 + col; gcol = gcol < 0 ? -gcol : (gcol > WW - 1 ? 2 * (WW - 1) - gcol : gcol);
            i32x4 u = *(const i32x4*)(fb + (size_t)(grow * WW + gcol) * CC + p * 64 + slot * 8);
            *(i32x4*)(lds + (row * 66 + col) * 128 + ((slot ^ (col & 7)) << 4)) = u;
        }
        __syncthreads();

        #pragma unroll
        for (int ky = 0; ky < 3; ++ky) {
            #pragma unroll
            for (int kx = 0; kx < 3; ++kx) {
                int tap = ky * 3 + kx;
                #pragma unroll
                for (int kcl = 0; kcl < 2; ++kcl) {
                    int kcg = p * 2 + kcl;
                    bs8 bf0 = wbp[((tap * 4 + kcg) * 8 + wid * 2 + 0) * 64 + lane];
                    bs8 bf1 = wbp[((tap * 4 + kcg) * 8 + wid * 2 + 1) * 64 + lane];
                    #pragma unroll
                    for (int ri = 0; ri < 2; ++ri) {
                        int sr = ri + ky;                 // staged row 0..3
                        #pragma unroll
                        for (int pf = 0; pf < 4; ++pf) {
                            bs8 a = *(const bs8*)(lds + sr * 8448 + pf * 2048
                                                  + basex[kx] + xr6[kx][kcl]);
                            acc[ri][pf][0] = __builtin_amdgcn_mfma_f32_16x16x32_bf16(bf0, a, acc[ri][pf][0], 0, 0, 0);
                            acc[ri][pf][1] = __builtin_amdgcn_mfma_f32_16x16x32_bf16(bf1, a, acc[ri][pf][1], 0, 0, 0);
                        }
                    }
                }
            }
        }
    }

    // f32 output store (D: row = oc_local = l4*4+r, col = px = pf*16+l15)
    #pragma unroll
    for (int ri = 0; ri < 2; ++ri) {
        #pragma unroll
        for (int pf = 0; pf < 4; ++pf) {
            int px = pf * 16 + l15;
            #pragma unroll
            for (int of = 0; of < 2; ++of) {
                #pragma unroll
                for (int r = 0; r < 4; ++r) {
                    int oc = wid * 32 + of * 16 + l4 * 4 + r;
                    out_conv[((size_t)b * CC + oc) * HWW + (h0 + ri) * WW + w0 + px] =
                        acc[ri][pf][of][r];
                }
            }
        }
    }

    // pool partials, coalesced [b][blk][oc] (no atomics)
    int blk = h2 * 5 + x;                             // 0..239 within b
    float* pp = pool_partial + ((size_t)b * NBLK + blk) * CC;
    #pragma unroll
    for (int of = 0; of < 2; ++of) {
        #pragma unroll
        for (int r = 0; r < 4; ++r) {
            float v = 0.f;
            #pragma unroll
            for (int ri = 0; ri < 2; ++ri)
                #pragma unroll
                for (int pf = 0; pf < 4; ++pf)
                    v += acc[ri][pf][of][r];
            v += __shfl_xor(v, 1, 64);
            v += __shfl_xor(v, 2, 64);
            v += __shfl_xor(v, 4, 64);
            v += __shfl_xor(v, 8, 64);
            if (l15 == 0)
                pp[wid * 32 + of * 16 + l4 * 4 + r] = v;
        }
    }
}

// ---------------------------------------------------------------------------
// Kernel 4: reduce NBLK per-block partials per (b,c) plane -> mean
// ---------------------------------------------------------------------------
__global__ __launch_bounds__(256) void pool_kernel(
    const float* __restrict__ partial, float* __restrict__ pool)
{
    int plane = blockIdx.x;                // 0..511  (b*CC + c)
    int b = plane >> 7, c = plane & 127;
    float s = 0.f;
    for (int i = threadIdx.x; i < NBLK; i += 256)
        s += partial[((size_t)b * NBLK + i) * CC + c];
    #pragma unroll
    for (int off = 32; off; off >>= 1) s += __shfl_down(s, off);
    __shared__ float wsum[4];
    if ((threadIdx.x & 63) == 0) wsum[threadIdx.x >> 6] = s;
    __syncthreads();
    if (threadIdx.x == 0)
        pool[plane] = (wsum[0] + wsum[1] + wsum[2] + wsum[3]) / (float)HWW;
}

// ---------------------------------------------------------------------------
// Kernel 5: SE MLP -> gate
// ---------------------------------------------------------------------------
__global__ __launch_bounds__(256) void segate_kernel(
    const float* __restrict__ pool, const float* __restrict__ w1,
    const float* __restrict__ w2, float* __restrict__ gate)
{
    __shared__ float hidden[BB * 8];
    int t = threadIdx.x;
    if (t < BB * 8) {
        int b = t / 8, r = t % 8;
        float s = 0.f;
        for (int c = 0; c < CC; ++c) s = fmaf(pool[b * CC + c], w1[r * CC + c], s);
        hidden[t] = fmaxf(s, 0.f);
    }
    __syncthreads();
    for (int idx = t; idx < BB * CC; idx += 256) {
        int b = idx / CC, c = idx % CC;
        float s = 0.f;
        #pragma unroll
        for (int r = 0; r < 8; ++r) s = fmaf(hidden[b * 8 + r], w2[c * 8 + r], s);
        gate[idx] = 1.f / (1.f + expf(-s));
    }
}

// ---------------------------------------------------------------------------
// Kernel 6: out = elu(conv * gate), float4 vectorized (in place on d_out)
// ---------------------------------------------------------------------------
__global__ __launch_bounds__(256) void elu_kernel(
    float* __restrict__ out, const float* __restrict__ gate)
{
    size_t i4 = ((size_t)blockIdx.x * 256 + threadIdx.x) * 4;
    int plane = (int)(i4 / HWW);           // 4 consecutive elems stay in one plane
    float g = gate[plane];
    float4 v = *(float4*)(out + i4);
    v.x *= g; v.y *= g; v.z *= g; v.w *= g;
    v.x = v.x > 0.f ? v.x : expm1f(v.x);
    v.y = v.y > 0.f ? v.y : expm1f(v.y);
    v.z = v.z > 0.f ? v.z : expm1f(v.z);
    v.w = v.w > 0.f ? v.w : expm1f(v.w);
    *(float4*)(out + i4) = v;
}

// ---------------------------------------------------------------------------
extern "C" void kernel_launch(void* const* d_in, const int* in_sizes, int n_in,
                              void* d_out, int out_size, void* d_ws, size_t ws_size,
                              hipStream_t stream)
{
    (void)in_sizes; (void)n_in; (void)out_size; (void)ws_size;
    const float* t_feat      = (const float*)d_in[0];
    const float* s_feat      = (const float*)d_in[1];
    const float* directs     = (const float*)d_in[2];
    const int*   image_shape = (const int*)d_in[3];
    const float* q_w  = (const float*)d_in[4];
    const float* q_b  = (const float*)d_in[5];
    const float* k_w  = (const float*)d_in[6];
    const float* k_b  = (const float*)d_in[7];
    const float* ce_w = (const float*)d_in[8];
    const float* ce_b = (const float*)d_in[9];
    const float* fa_w = (const float*)d_in[10];
    const float* fa_b = (const float*)d_in[11];
    const float* redu_w = (const float*)d_in[12];
    const float* se_w1  = (const float*)d_in[13];
    const float* se_w2  = (const float*)d_in[14];

    float* out      = (float*)d_out;
    float* prob_out = out + (size_t)BB * CC * HWW;   // second output region

    // ws layout (floats):
    //   [0, QK)            ws_q      (channel-last; aliased by ws_cost after sim)
    //   [QK, 2QK)          ws_k      (channel-last; dead after simcost)
    //   [2QK, 2QK+F/2)     fused bf16 (F/2 floats worth); wqk aliases its start
    //   [2QK+F/2, ...)     pool partials (BB*NBLK*CC f), then wce+wb frags
    //   [2QK+F, ...)       ws_pool, ws_gate
    const size_t QK = (size_t)BB * CRR * HWW;        // 3,932,160
    const size_t F  = (size_t)BB * CC * HWW;         // 15,728,640
    float* ws       = (float*)d_ws;
    float* ws_q     = ws;
    float* ws_k     = ws + QK;
    float* ws_cost  = ws_q;                                // aliases ws_q
    unsigned short* ws_fused = (unsigned short*)(ws + 2 * QK);
    float* ws_partial = ws + 2 * QK + F / 2;               // BB*NBLK*CC floats
    unsigned short* ws_wce = (unsigned short*)(ws_partial + (size_t)BB * NBLK * CC);
    unsigned short* ws_wb  = ws_wce + 4096;                // 147456 shorts
    float* ws_pool  = ws + 2 * QK + F;
    float* ws_gate  = ws_pool + BB * CC;
    unsigned short* ws_wqk = (unsigned short*)ws_fused;    // dead once fuse writes

    repack_all_kernel<<<624, 256, 0, stream>>>(q_w, k_w, ce_w, redu_w,
                                               ws_wqk, ws_wce, ws_wb);
    qk_mfma_kernel<<<BB * HWW / 64, 256, 0, stream>>>(t_feat, s_feat, ws_wqk,
                                                      q_b, k_b, ws_q, ws_k);
    simcost_kernel<<<dim3(WW / SC_TILE, HH, BB), 256, 0, stream>>>(
        directs, image_shape, ws_q, ws_k, prob_out, ws_cost);
    fuse_mfma_kernel<<<BB * HWW / 64, 256, 0, stream>>>(t_feat, ws_wce, ce_b, fa_w, fa_b,
                                                        ws_cost, ws_fused);
    conv_mfma_kernel<<<5 * (HH / 2) * BB, 256, 0, stream>>>(ws_fused, ws_wb, out, ws_partial);
    pool_kernel<<<BB * CC, 256, 0, stream>>>(ws_partial, ws_pool);
    segate_kernel<<<1, 256, 0, stream>>>(ws_pool, se_w1, se_w2, ws_gate);
    elu_kernel<<<(BB * CC * HWW) / 1024, 256, 0, stream>>>(out, ws_gate);
}

// Round 17
// 163.746 us; speedup vs baseline: 1.6040x; 1.6040x over previous
//
#include <hip/hip_runtime.h>
#include <math.h>

#define BB 4
#define CC 128
#define CRR 32
#define DD 24
#define HH 96
#define WW 320
#define HWW (HH*WW)   // 30720

typedef __attribute__((ext_vector_type(8))) short bs8;     // 8 bf16 (4 VGPR)
typedef __attribute__((ext_vector_type(4))) float f32x4;   // MFMA acc
typedef __attribute__((ext_vector_type(4))) int   i32x4;

static __device__ __forceinline__ unsigned short f2bf(float x) {
    unsigned int u = __float_as_uint(x);
    unsigned int r = (u + 0x7fffu + ((u >> 16) & 1u)) >> 16;   // RNE
    return (unsigned short)r;
}

// ---------------------------------------------------------------------------
// Merged repack: q_w/k_w + ce_w + redu_w -> bf16 fragments. 159744 elems.
// wce/wb live in the spare upper-fused region (never clobbered).
// ---------------------------------------------------------------------------
__global__ __launch_bounds__(256) void repack_all_kernel(
    const float* __restrict__ q_w, const float* __restrict__ k_w,
    const float* __restrict__ ce_w, const float* __restrict__ redu_w,
    unsigned short* __restrict__ wqk, unsigned short* __restrict__ wce,
    unsigned short* __restrict__ wb)
{
    int idx = blockIdx.x * 256 + threadIdx.x;
    if (idx < 8192) {
        int j   = idx & 7;
        int l   = (idx >> 3) & 63;
        int kc  = (idx >> 9) & 3;
        int ofh = (idx >> 11) & 1;
        int g   = idx >> 12;
        const float* w = g ? k_w : q_w;
        int oc = ofh * 16 + (l & 15);
        int ic = kc * 32 + (l >> 4) * 8 + j;
        wqk[idx] = f2bf(w[oc * CC + ic]);
    } else if (idx < 12288) {
        int i   = idx - 8192;
        int j   = i & 7;
        int l   = (i >> 3) & 63;
        int ofg = (i >> 9) & 7;
        int oc = ofg * 16 + (l & 15);
        int ic = (l >> 4) * 8 + j;
        wce[i] = f2bf(ce_w[oc * CRR + ic]);
    } else {
        int i2 = idx - 12288;                    // < 147456
        int j    = i2 & 7;
        int l    = (i2 >> 3) & 63;
        int rest = i2 >> 9;
        int ocf  = rest & 7;
        int kc   = (rest >> 3) & 3;
        int tap  = rest >> 5;                    // 0..8
        int oc = ocf * 16 + (l & 15);
        int ic = kc * 32 + (l >> 4) * 8 + j;
        wb[i2] = f2bf(redu_w[(size_t)(oc * CC + ic) * 9 + tap]);
    }
}

// ---------------------------------------------------------------------------
// Kernel 1: q/k 1x1 conv + bias + l2norm via bf16 MFMA (weights = A operand).
// Output layout: CHANNEL-LAST  ws_q/ws_k[(b*HWW+px)*32 + c].
// ---------------------------------------------------------------------------
__global__ __launch_bounds__(256) void qk_mfma_kernel(
    const float* __restrict__ t_feat, const float* __restrict__ s_feat,
    const unsigned short* __restrict__ wqk,
    const float* __restrict__ q_b, const float* __restrict__ k_b,
    float* __restrict__ ws_q, float* __restrict__ ws_k)
{
    __shared__ __align__(16) unsigned char lds[2 * 64 * 16 * 16];   // 32 KB
    int tid  = threadIdx.x;
    int lane = tid & 63;
    int wid  = __builtin_amdgcn_readfirstlane(tid >> 6);
    int g = wid >> 1, ofh = wid & 1;
    int p0 = blockIdx.x * 64;
    int b = p0 / HWW, rem0 = p0 % HWW;

    for (int ci = tid; ci < 2 * 64 * 16; ci += 256) {
        int px   = ci & 63;
        int slot = (ci >> 6) & 15;
        int m    = ci >> 10;
        const float* src = (m ? s_feat : t_feat)
                         + (size_t)b * CC * HWW + (size_t)(slot * 8) * HWW + rem0 + px;
        i32x4 u;
        #pragma unroll
        for (int j = 0; j < 4; ++j) {
            unsigned short lo = f2bf(src[(size_t)(2 * j) * HWW]);
            unsigned short hi = f2bf(src[(size_t)(2 * j + 1) * HWW]);
            u[j] = (int)((unsigned int)lo | ((unsigned int)hi << 16));
        }
        int addr = m * 16384 + px * 256 + ((slot ^ (px & 7)) << 4);
        *(i32x4*)(lds + addr) = u;
    }
    __syncthreads();

    int l15 = lane & 15, l4 = lane >> 4;
    f32x4 acc[4];
    #pragma unroll
    for (int pf = 0; pf < 4; ++pf) acc[pf] = (f32x4){0.f, 0.f, 0.f, 0.f};

    const bs8* wp = (const bs8*)wqk + (size_t)(g * 2 + ofh) * 4 * 64;
    #pragma unroll
    for (int kc = 0; kc < 4; ++kc) {
        bs8 bf = wp[kc * 64 + lane];
        #pragma unroll
        for (int pf = 0; pf < 4; ++pf) {
            int addr = g * 16384 + (pf * 16 + l15) * 256 + (((kc * 4 + l4) ^ (l15 & 7)) << 4);
            bs8 a = *(const bs8*)(lds + addr);
            acc[pf] = __builtin_amdgcn_mfma_f32_16x16x32_bf16(bf, a, acc[pf], 0, 0, 0);
        }
    }

    float4 bias4 = *(const float4*)((g ? k_b : q_b) + ofh * 16 + l4 * 4);
    float np[4];
    #pragma unroll
    for (int pf = 0; pf < 4; ++pf) {
        float s = 0.f;
        #pragma unroll
        for (int r = 0; r < 4; ++r) {
            float v = acc[pf][r] + ((const float*)&bias4)[r];
            acc[pf][r] = v;
            s = fmaf(v, v, s);
        }
        s += __shfl_xor(s, 16, 64);
        s += __shfl_xor(s, 32, 64);
        np[pf] = s;
    }
    __syncthreads();    // A tiles dead; reuse LDS for norm exchange
    float* fl = (float*)lds;   // [4 waves][64 px]
    if (l4 == 0) {
        #pragma unroll
        for (int pf = 0; pf < 4; ++pf)
            fl[(g * 2 + ofh) * 64 + pf * 16 + l15] = np[pf];
    }
    __syncthreads();

    float* dst = (g ? ws_k : ws_q) + ((size_t)b * HWW + rem0) * CRR;
    #pragma unroll
    for (int pf = 0; pf < 4; ++pf) {
        int px = pf * 16 + l15;
        float tot = fl[(g * 2) * 64 + px] + fl[(g * 2 + 1) * 64 + px];
        float inv = 1.f / fmaxf(sqrtf(tot), 1e-12f);
        float4 v;
        v.x = acc[pf][0] * inv; v.y = acc[pf][1] * inv;
        v.z = acc[pf][2] * inv; v.w = acc[pf][3] * inv;
        *(float4*)(dst + (size_t)px * CRR + ofh * 16 + l4 * 4) = v;
    }
}

// ---------------------------------------------------------------------------
// Kernel 2: sim + (no-max) online softmax + cost, single gather pass over
// an LDS-staged k-row segment.  One-sided halo (directs fixes shift sign).
// ---------------------------------------------------------------------------
#define SC_TILE 64
#define SC_NCOLS 114
__global__ __launch_bounds__(256) void simcost_kernel(
    const float* __restrict__ directs, const int* __restrict__ image_shape,
    const float* __restrict__ ws_q, const float* __restrict__ ws_k,
    float* __restrict__ prob_out, float* __restrict__ ws_cost)
{
    __shared__ __align__(16) unsigned char kl[SC_NCOLS * 128];
    int tid = threadIdx.x;
    int b = blockIdx.z, h = blockIdx.y, w0 = blockIdx.x * SC_TILE;

    float rel = 640.0f / (float)image_shape[3];
    float fscale = rel * directs[b] * (float)(WW - 1);
    int base = (fscale >= 0.f) ? w0 : (w0 - 49);

    const float* krow = ws_k + ((size_t)b * HWW + h * WW) * CRR;
    for (int i = tid; i < SC_NCOLS * 8; i += 256) {
        int col = i >> 3, j = i & 7;
        int gc = min(max(base + col, 0), WW - 1);
        float4 v = *(const float4*)(krow + (size_t)gc * CRR + j * 4);
        *(float4*)(kl + col * 128 + ((j ^ (col & 7)) << 4)) = v;
    }
    __syncthreads();

    int quarter = tid & 3;
    int pxl = tid >> 2;                       // 0..63
    int w = w0 + pxl;
    int rem = h * WW + w;
    size_t p = (size_t)b * HWW + rem;

    float4 q0, q1;
    {
        const float4* qb = (const float4*)(ws_q + p * CRR + quarter * 8);
        q0 = qb[0]; q1 = qb[1];
    }

    float e[DD];
    float Z = 0.f;
    float4 c0 = {0.f,0.f,0.f,0.f}, c1 = {0.f,0.f,0.f,0.f};
    int j0 = quarter * 2, j1 = quarter * 2 + 1;

    #pragma unroll
    for (int d = 0; d < DD; ++d) {
        float disp = 0.3f * (float)d / 23.0f;
        float fx = fminf(fmaxf((float)w + disp * fscale, 0.f), (float)(WW - 1));
        int ix0 = (int)floorf(fx);
        int ix1 = min(ix0 + 1, WW - 1);
        float w1 = fx - (float)ix0;
        int ca = ix0 - base, cb2 = ix1 - base;
        float4 a0 = *(const float4*)(kl + ca  * 128 + ((j0 ^ (ca  & 7)) << 4));
        float4 a1 = *(const float4*)(kl + ca  * 128 + ((j1 ^ (ca  & 7)) << 4));
        float4 b0 = *(const float4*)(kl + cb2 * 128 + ((j0 ^ (cb2 & 7)) << 4));
        float4 b1 = *(const float4*)(kl + cb2 * 128 + ((j1 ^ (cb2 & 7)) << 4));
        float4 w0v, w1v;
        w0v.x = fmaf(w1, b0.x - a0.x, a0.x);
        w0v.y = fmaf(w1, b0.y - a0.y, a0.y);
        w0v.z = fmaf(w1, b0.z - a0.z, a0.z);
        w0v.w = fmaf(w1, b0.w - a0.w, a0.w);
        w1v.x = fmaf(w1, b1.x - a1.x, a1.x);
        w1v.y = fmaf(w1, b1.y - a1.y, a1.y);
        w1v.z = fmaf(w1, b1.z - a1.z, a1.z);
        w1v.w = fmaf(w1, b1.w - a1.w, a1.w);
        float s = 0.f;
        s = fmaf(q0.x, w0v.x, s); s = fmaf(q0.y, w0v.y, s);
        s = fmaf(q0.z, w0v.z, s); s = fmaf(q0.w, w0v.w, s);
        s = fmaf(q1.x, w1v.x, s); s = fmaf(q1.y, w1v.y, s);
        s = fmaf(q1.z, w1v.z, s); s = fmaf(q1.w, w1v.w, s);
        s += __shfl_xor(s, 1, 64);
        s += __shfl_xor(s, 2, 64);
        float ee = __expf(s);
        e[d] = ee;
        Z += ee;
        c0.x = fmaf(ee, w0v.x, c0.x); c0.y = fmaf(ee, w0v.y, c0.y);
        c0.z = fmaf(ee, w0v.z, c0.z); c0.w = fmaf(ee, w0v.w, c0.w);
        c1.x = fmaf(ee, w1v.x, c1.x); c1.y = fmaf(ee, w1v.y, c1.y);
        c1.z = fmaf(ee, w1v.z, c1.z); c1.w = fmaf(ee, w1v.w, c1.w);
    }
    float inv = 1.f / Z;
    if (quarter == 0) {
        #pragma unroll
        for (int d = 0; d < DD; ++d)
            prob_out[((size_t)b * DD + d) * HWW + rem] = e[d] * inv;
    }
    c0.x *= inv; c0.y *= inv; c0.z *= inv; c0.w *= inv;
    c1.x *= inv; c1.y *= inv; c1.z *= inv; c1.w *= inv;
    float4* cb = (float4*)(ws_cost + p * CRR + quarter * 8);
    cb[0] = c0; cb[1] = c1;
}

// ---------------------------------------------------------------------------
// Kernel 2c: cost-expand via MFMA (weights = A) + alpha + fuse.
// Writes fused as bf16 CHANNEL-LAST [px][128].
// ---------------------------------------------------------------------------
__global__ __launch_bounds__(256) void fuse_mfma_kernel(
    const float* __restrict__ t_feat, const unsigned short* __restrict__ wce,
    const float* __restrict__ ce_b, const float* __restrict__ fa_w,
    const float* __restrict__ fa_b,
    const float* __restrict__ ws_cost, unsigned short* __restrict__ fused)
{
    __shared__ __align__(16) unsigned char ldsA[64 * 64];   // 64px x 32c bf16
    __shared__ float lds_pa[64][4];
    __shared__ float lds_alpha[64];
    int tid  = threadIdx.x;
    int lane = tid & 63;
    int wid  = __builtin_amdgcn_readfirstlane(tid >> 6);
    int p0 = blockIdx.x * 64;
    int b = p0 / HWW, rem0 = p0 % HWW;

    {   // stage cost tile bf16 (1 slot of 8ch per thread)
        int px = tid & 63, slot = tid >> 6;
        const float* src = ws_cost + (size_t)(p0 + px) * CRR + slot * 8;
        i32x4 u;
        #pragma unroll
        for (int j = 0; j < 4; ++j) {
            unsigned short lo = f2bf(src[2 * j]);
            unsigned short hi = f2bf(src[2 * j + 1]);
            u[j] = (int)((unsigned int)lo | ((unsigned int)hi << 16));
        }
        int addr = px * 64 + ((slot ^ (px & 3)) << 4);
        *(i32x4*)(ldsA + addr) = u;
    }
    __syncthreads();

    int l15 = lane & 15, l4 = lane >> 4;
    f32x4 acc[4][2];
    #pragma unroll
    for (int pf = 0; pf < 4; ++pf)
        #pragma unroll
        for (int of = 0; of < 2; ++of)
            acc[pf][of] = (f32x4){0.f, 0.f, 0.f, 0.f};

    const bs8* wp = (const bs8*)wce;
    #pragma unroll
    for (int pf = 0; pf < 4; ++pf) {
        int row = pf * 16 + l15;
        bs8 a = *(const bs8*)(ldsA + row * 64 + ((l4 ^ (l15 & 3)) << 4));
        #pragma unroll
        for (int of = 0; of < 2; ++of) {
            bs8 bf = wp[(wid * 2 + of) * 64 + lane];
            acc[pf][of] = __builtin_amdgcn_mfma_f32_16x16x32_bf16(bf, a, acc[pf][of], 0, 0, 0);
        }
    }

    // epilogue: oc = wid*32 + of*16 + l4*4 + r ; px = pf*16 + l15
    const float* tb = t_feat + (size_t)b * CC * HWW + rem0;
    float tv[4][2][4];
    float pa[4];
    #pragma unroll
    for (int pf = 0; pf < 4; ++pf) pa[pf] = 0.f;

    #pragma unroll
    for (int of = 0; of < 2; ++of) {
        int ocb = wid * 32 + of * 16 + l4 * 4;
        float4 cb4 = *(const float4*)(ce_b + ocb);
        float4 f14 = *(const float4*)(fa_w + ocb);
        float4 f24 = *(const float4*)(fa_w + CC + ocb);
        #pragma unroll
        for (int pf = 0; pf < 4; ++pf) {
            int px = pf * 16 + l15;
            #pragma unroll
            for (int r = 0; r < 4; ++r) {
                float ce = acc[pf][of][r] + ((const float*)&cb4)[r];
                acc[pf][of][r] = ce;
                float t = tb[(size_t)(ocb + r) * HWW + px];
                tv[pf][of][r] = t;
                pa[pf] = fmaf(((const float*)&f14)[r], t,
                              fmaf(((const float*)&f24)[r], ce, pa[pf]));
            }
        }
    }
    #pragma unroll
    for (int pf = 0; pf < 4; ++pf) {
        float v = pa[pf];
        v += __shfl_xor(v, 16, 64);
        v += __shfl_xor(v, 32, 64);
        if (l4 == 0) lds_pa[pf * 16 + l15][wid] = v;
    }
    __syncthreads();
    if (tid < 64) {
        float s = lds_pa[tid][0] + lds_pa[tid][1] + lds_pa[tid][2] + lds_pa[tid][3] + fa_b[0];
        lds_alpha[tid] = 1.f / (1.f + expf(-s));
    }
    __syncthreads();

    #pragma unroll
    for (int pf = 0; pf < 4; ++pf) {
        int px = pf * 16 + l15;
        float alpha = lds_alpha[px];
        unsigned short* dst = fused + (size_t)(p0 + px) * CC;
        #pragma unroll
        for (int of = 0; of < 2; ++of) {
            int ocb = wid * 32 + of * 16 + l4 * 4;
            float v0 = alpha * tv[pf][of][0] + (1.f - alpha) * acc[pf][of][0];
            float v1 = alpha * tv[pf][of][1] + (1.f - alpha) * acc[pf][of][1];
            float v2 = alpha * tv[pf][of][2] + (1.f - alpha) * acc[pf][of][2];
            float v3 = alpha * tv[pf][of][3] + (1.f - alpha) * acc[pf][of][3];
            uint2 u;
            u.x = (unsigned int)f2bf(v0) | ((unsigned int)f2bf(v1) << 16);
            u.y = (unsigned int)f2bf(v2) | ((unsigned int)f2bf(v3) << 16);
            *(uint2*)(dst + ocb) = u;
        }
    }
}

// ---------------------------------------------------------------------------
// Kernel 3: 3x3 reflect-pad conv via bf16 MFMA (weights = A operand).
// R11 structure (wave owns 32 oc; B-frags reused across 4 pf; 16-slot
// matched swizzle) + XCD-aware bijective block swizzle (1920 blocks, 8 XCDs
// -> each XCD gets a contiguous half-batch: halo rows hit its own L2).
// Pool partials written coalesced [b][blk][oc] (no atomics).
// ---------------------------------------------------------------------------
__global__ __launch_bounds__(256, 3) void conv_mfma_kernel(
    const unsigned short* __restrict__ fused, const unsigned short* __restrict__ wb,
    float* __restrict__ out_conv, float* __restrict__ pool_partial)
{
    __shared__ __align__(16) unsigned char lds[3 * 66 * 256];
    int tid  = threadIdx.x;
    int lane = tid & 63;
    int wid  = __builtin_amdgcn_readfirstlane(tid >> 6);

    // XCD swizzle: 1920 blocks, 8 XCDs, 240 contiguous per XCD
    int bid = blockIdx.x;
    int swz = (bid & 7) * 240 + (bid >> 3);
    int x  = swz % 5;
    int h  = (swz / 5) % HH;
    int b  = swz / (5 * HH);
    int w0 = x * 64;

    const unsigned short* fb = fused + (size_t)b * HWW * CC;

    // stage: slot-fastest; swizzle slot ^ (col&15)
    for (int ci = tid; ci < 3 * 66 * 16; ci += 256) {
        int row  = ci / 1056;
        int r2   = ci - row * 1056;
        int col  = r2 >> 4;
        int slot = r2 & 15;
        int grow = h - 1 + row; grow = grow < 0 ? 1 : (grow > HH - 1 ? HH - 2 : grow);
        int gcol = w0 - 1 + col; gcol = gcol < 0 ? -gcol : (gcol > WW - 1 ? 2 * (WW - 1) - gcol : gcol);
        i32x4 u = *(const i32x4*)(fb + (size_t)(grow * WW + gcol) * CC + slot * 8);
        *(i32x4*)(lds + (row * 66 + col) * 256 + ((slot ^ (col & 15)) << 4)) = u;
    }
    __syncthreads();

    f32x4 acc[4][2];
    #pragma unroll
    for (int pf = 0; pf < 4; ++pf)
        #pragma unroll
        for (int of = 0; of < 2; ++of)
            acc[pf][of] = (f32x4){0.f, 0.f, 0.f, 0.f};

    int l15 = lane & 15, l4 = lane >> 4;
    const bs8* wbp = (const bs8*)wb;

    // precompute the 12 swizzle-XOR variants and 3 column bases
    int basex[3], xr12[3][4];
    #pragma unroll
    for (int kx = 0; kx < 3; ++kx) {
        basex[kx] = (l15 + kx) * 256;
        #pragma unroll
        for (int kc = 0; kc < 4; ++kc)
            xr12[kx][kc] = ((kc * 4 + l4) ^ ((l15 + kx) & 15)) << 4;
    }

    #pragma unroll
    for (int ky = 0; ky < 3; ++ky) {
        #pragma unroll
        for (int kx = 0; kx < 3; ++kx) {
            int tap = ky * 3 + kx;
            #pragma unroll
            for (int kc = 0; kc < 4; ++kc) {
                bs8 a[4];
                #pragma unroll
                for (int pf = 0; pf < 4; ++pf)
                    a[pf] = *(const bs8*)(lds + ky * 16896 + pf * 4096
                                          + basex[kx] + xr12[kx][kc]);
                bs8 bf0 = wbp[((tap * 4 + kc) * 8 + wid * 2 + 0) * 64 + lane];
                bs8 bf1 = wbp[((tap * 4 + kc) * 8 + wid * 2 + 1) * 64 + lane];
                #pragma unroll
                for (int pf = 0; pf < 4; ++pf) {
                    acc[pf][0] = __builtin_amdgcn_mfma_f32_16x16x32_bf16(bf0, a[pf], acc[pf][0], 0, 0, 0);
                    acc[pf][1] = __builtin_amdgcn_mfma_f32_16x16x32_bf16(bf1, a[pf], acc[pf][1], 0, 0, 0);
                }
            }
        }
    }

    // D: row = oc_local = l4*4+r, col = px = pf*16+l15
    #pragma unroll
    for (int pf = 0; pf < 4; ++pf) {
        int px = pf * 16 + l15;
        #pragma unroll
        for (int of = 0; of < 2; ++of) {
            #pragma unroll
            for (int r = 0; r < 4; ++r) {
                int oc = wid * 32 + of * 16 + l4 * 4 + r;
                out_conv[((size_t)b * CC + oc) * HWW + h * WW + w0 + px] = acc[pf][of][r];
            }
        }
    }

    // pool partials: coalesced [b][blk][oc] (no atomics)
    int blk = h * 5 + x;                           // 0..479 within b
    float* pp = pool_partial + ((size_t)b * 480 + blk) * CC;
    #pragma unroll
    for (int of = 0; of < 2; ++of) {
        #pragma unroll
        for (int r = 0; r < 4; ++r) {
            float v = acc[0][of][r] + acc[1][of][r] + acc[2][of][r] + acc[3][of][r];
            v += __shfl_xor(v, 1, 64);
            v += __shfl_xor(v, 2, 64);
            v += __shfl_xor(v, 4, 64);
            v += __shfl_xor(v, 8, 64);
            if (l15 == 0)
                pp[wid * 32 + of * 16 + l4 * 4 + r] = v;
        }
    }
}

// ---------------------------------------------------------------------------
// Kernel 4: reduce 480 per-block partials per (b,c) plane -> mean
// ---------------------------------------------------------------------------
__global__ __launch_bounds__(256) void pool_kernel(
    const float* __restrict__ partial, float* __restrict__ pool)
{
    int plane = blockIdx.x;                // 0..511  (b*CC + c)
    int b = plane >> 7, c = plane & 127;
    float s = 0.f;
    for (int i = threadIdx.x; i < 480; i += 256)
        s += partial[((size_t)b * 480 + i) * CC + c];
    #pragma unroll
    for (int off = 32; off; off >>= 1) s += __shfl_down(s, off);
    __shared__ float wsum[4];
    if ((threadIdx.x & 63) == 0) wsum[threadIdx.x >> 6] = s;
    __syncthreads();
    if (threadIdx.x == 0)
        pool[plane] = (wsum[0] + wsum[1] + wsum[2] + wsum[3]) / (float)HWW;
}

// ---------------------------------------------------------------------------
// Kernel 5: SE MLP -> gate
// ---------------------------------------------------------------------------
__global__ __launch_bounds__(256) void segate_kernel(
    const float* __restrict__ pool, const float* __restrict__ w1,
    const float* __restrict__ w2, float* __restrict__ gate)
{
    __shared__ float hidden[BB * 8];
    int t = threadIdx.x;
    if (t < BB * 8) {
        int b = t / 8, r = t % 8;
        float s = 0.f;
        for (int c = 0; c < CC; ++c) s = fmaf(pool[b * CC + c], w1[r * CC + c], s);
        hidden[t] = fmaxf(s, 0.f);
    }
    __syncthreads();
    for (int idx = t; idx < BB * CC; idx += 256) {
        int b = idx / CC, c = idx % CC;
        float s = 0.f;
        #pragma unroll
        for (int r = 0; r < 8; ++r) s = fmaf(hidden[b * 8 + r], w2[c * 8 + r], s);
        gate[idx] = 1.f / (1.f + expf(-s));
    }
}

// ---------------------------------------------------------------------------
// Kernel 6: out = elu(conv * gate), float4 vectorized (in place on d_out)
// ---------------------------------------------------------------------------
__global__ __launch_bounds__(256) void elu_kernel(
    float* __restrict__ out, const float* __restrict__ gate)
{
    size_t i4 = ((size_t)blockIdx.x * 256 + threadIdx.x) * 4;
    int plane = (int)(i4 / HWW);           // 4 consecutive elems stay in one plane
    float g = gate[plane];
    float4 v = *(float4*)(out + i4);
    v.x *= g; v.y *= g; v.z *= g; v.w *= g;
    v.x = v.x > 0.f ? v.x : expm1f(v.x);
    v.y = v.y > 0.f ? v.y : expm1f(v.y);
    v.z = v.z > 0.f ? v.z : expm1f(v.z);
    v.w = v.w > 0.f ? v.w : expm1f(v.w);
    *(float4*)(out + i4) = v;
}

// ---------------------------------------------------------------------------
extern "C" void kernel_launch(void* const* d_in, const int* in_sizes, int n_in,
                              void* d_out, int out_size, void* d_ws, size_t ws_size,
                              hipStream_t stream)
{
    (void)in_sizes; (void)n_in; (void)out_size; (void)ws_size;
    const float* t_feat      = (const float*)d_in[0];
    const float* s_feat      = (const float*)d_in[1];
    const float* directs     = (const float*)d_in[2];
    const int*   image_shape = (const int*)d_in[3];
    const float* q_w  = (const float*)d_in[4];
    const float* q_b  = (const float*)d_in[5];
    const float* k_w  = (const float*)d_in[6];
    const float* k_b  = (const float*)d_in[7];
    const float* ce_w = (const float*)d_in[8];
    const float* ce_b = (const float*)d_in[9];
    const float* fa_w = (const float*)d_in[10];
    const float* fa_b = (const float*)d_in[11];
    const float* redu_w = (const float*)d_in[12];
    const float* se_w1  = (const float*)d_in[13];
    const float* se_w2  = (const float*)d_in[14];

    float* out      = (float*)d_out;
    float* prob_out = out + (size_t)BB * CC * HWW;   // second output region

    // ws layout (floats):
    //   [0, QK)            ws_q      (channel-last; aliased by ws_cost after sim)
    //   [QK, 2QK)          ws_k      (channel-last; dead after simcost)
    //   [2QK, 2QK+F/2)     fused bf16 (F/2 floats worth); wqk aliases its start
    //   [2QK+F/2, ...)     pool partials (245760 f), then wce+wb frags
    //   [2QK+F, ...)       ws_pool, ws_gate
    const size_t QK = (size_t)BB * CRR * HWW;        // 3,932,160
    const size_t F  = (size_t)BB * CC * HWW;         // 15,728,640
    float* ws       = (float*)d_ws;
    float* ws_q     = ws;
    float* ws_k     = ws + QK;
    float* ws_cost  = ws_q;                                // aliases ws_q
    unsigned short* ws_fused = (unsigned short*)(ws + 2 * QK);
    float* ws_partial = ws + 2 * QK + F / 2;               // 480*BB*CC floats
    unsigned short* ws_wce = (unsigned short*)(ws_partial + (size_t)BB * CC * 480);
    unsigned short* ws_wb  = ws_wce + 4096;                // 147456 shorts
    float* ws_pool  = ws + 2 * QK + F;
    float* ws_gate  = ws_pool + BB * CC;
    unsigned short* ws_wqk = (unsigned short*)ws_fused;    // dead once fuse writes

    repack_all_kernel<<<624, 256, 0, stream>>>(q_w, k_w, ce_w, redu_w,
                                               ws_wqk, ws_wce, ws_wb);
    qk_mfma_kernel<<<BB * HWW / 64, 256, 0, stream>>>(t_feat, s_feat, ws_wqk,
                                                      q_b, k_b, ws_q, ws_k);
    simcost_kernel<<<dim3(WW / SC_TILE, HH, BB), 256, 0, stream>>>(
        directs, image_shape, ws_q, ws_k, prob_out, ws_cost);
    fuse_mfma_kernel<<<BB * HWW / 64, 256, 0, stream>>>(t_feat, ws_wce, ce_b, fa_w, fa_b,
                                                        ws_cost, ws_fused);
    conv_mfma_kernel<<<5 * HH * BB, 256, 0, stream>>>(ws_fused, ws_wb, out, ws_partial);
    pool_kernel<<<BB * CC, 256, 0, stream>>>(ws_partial, ws_pool);
    segate_kernel<<<1, 256, 0, stream>>>(ws_pool, se_w1, se_w2, ws_gate);
    elu_kernel<<<(BB * CC * HWW) / 1024, 256, 0, stream>>>(out, ws_gate);
}